// Round 13
// baseline (8711.286 us; speedup 1.0000x reference)
//
#include <hip/hip_runtime.h>
#include <hip/hip_bf16.h>

#define Hd 768
#define Bd 32
#define Td 1024
#define Md (Bd*Td)

// scan: 8 groups (4 batches each) x 32 slices (24 rows each) = 256 WGs
#define NGRP 8
#define SPW   32
#define RPW   24          // rows per WG
#define BPG   4           // batches per group
#define THRS  384
#define RINGD 4
#define SENT_U 0x7FC00000u
#define RVALS (BPG*Hd)    // 3072 words per ring region
#define WSTR  769         // f32 per padded weight row (769 % 32 == 1 -> 2-way banks)
#define SMEM_BYTES (2*RPW*WSTR*4 + RVALS*4)   // 147648 + 12288 = 159936

typedef unsigned int u32x4 __attribute__((ext_vector_type(4)));

// ---------------- init: ring region 0 = h0, regions 1..3 = sentinel ----------------
__global__ __launch_bounds__(256) void k_init(const float* __restrict__ hid,
                                              unsigned* __restrict__ ring) {
    int i = blockIdx.x * 256 + threadIdx.x;          // 8*4*3072 = 98304 total
    const int grp = i / (RINGD * RVALS);
    const int rem = i % (RINGD * RVALS);
    const int r   = rem / RVALS;
    const int q   = rem % RVALS;
    const int bb  = q / Hd;
    const int k   = q % Hd;
    unsigned v = SENT_U;
    if (r == 0) v = ((const unsigned*)hid)[(grp * BPG + bb) * Hd + k];
    ring[i] = v;
}

// ---------------- phase 1: gi GEMM (unchanged) ----------------
__global__ __launch_bounds__(256, 2) void k_gemm(const float* __restrict__ A,
                                                 const float* __restrict__ Wih,
                                                 const float* __restrict__ bih,
                                                 float* __restrict__ giR,
                                                 float* __restrict__ giN) {
    __shared__ float As[16][68];
    __shared__ float Brs[16][68];
    __shared__ float Bns[16][68];
    const int tid = threadIdx.x;
    const int mb = blockIdx.x & 511;
    const int nb = blockIdx.x >> 9;
    const int lm = tid >> 2;
    const int lk = (tid & 3) << 2;
    const int tx = tid & 15;
    const int ty = tid >> 4;

    const float* pA = A   + (size_t)(mb * 64 + lm) * Hd + lk;
    const float* pR = Wih + (size_t)(nb * 64 + lm) * Hd + lk;
    const float* pN = Wih + (size_t)(2 * Hd + nb * 64 + lm) * Hd + lk;

    float accR[4][4] = {{0.f}};
    float accN[4][4] = {{0.f}};

    for (int kt = 0; kt < Hd; kt += 16) {
        float4 va = *(const float4*)(pA + kt);
        float4 vr = *(const float4*)(pR + kt);
        float4 vn = *(const float4*)(pN + kt);
        __syncthreads();
        As[lk+0][lm]=va.x; As[lk+1][lm]=va.y; As[lk+2][lm]=va.z; As[lk+3][lm]=va.w;
        Brs[lk+0][lm]=vr.x; Brs[lk+1][lm]=vr.y; Brs[lk+2][lm]=vr.z; Brs[lk+3][lm]=vr.w;
        Bns[lk+0][lm]=vn.x; Bns[lk+1][lm]=vn.y; Bns[lk+2][lm]=vn.z; Bns[lk+3][lm]=vn.w;
        __syncthreads();
        #pragma unroll
        for (int k = 0; k < 16; ++k) {
            float4 a4 = *(const float4*)&As[k][ty << 2];
            float4 r4 = *(const float4*)&Brs[k][tx << 2];
            float4 n4 = *(const float4*)&Bns[k][tx << 2];
            float av[4] = {a4.x, a4.y, a4.z, a4.w};
            float rv[4] = {r4.x, r4.y, r4.z, r4.w};
            float nv[4] = {n4.x, n4.y, n4.z, n4.w};
            #pragma unroll
            for (int i = 0; i < 4; ++i)
                #pragma unroll
                for (int j = 0; j < 4; ++j) {
                    accR[i][j] += av[i] * rv[j];
                    accN[i][j] += av[i] * nv[j];
                }
        }
    }

    const int m0 = mb * 64 + (ty << 2);
    const int g0 = nb * 64 + (tx << 2);
    float4 bR = *(const float4*)(bih + g0);
    float4 bN = *(const float4*)(bih + 2 * Hd + g0);
    #pragma unroll
    for (int i = 0; i < 4; ++i) {
        float4 oR = { accR[i][0]+bR.x, accR[i][1]+bR.y, accR[i][2]+bR.z, accR[i][3]+bR.w };
        float4 oN = { accN[i][0]+bN.x, accN[i][1]+bN.y, accN[i][2]+bN.z, accN[i][3]+bN.w };
        *(float4*)(giR + (size_t)(m0 + i) * Hd + g0) = oR;
        *(float4*)(giN + (size_t)(m0 + i) * Hd + g0) = oN;
    }
}

// ---------------- phase 2: sentinel-ring scan, LDS weights (conflict-free) ----
// 256 WGs = 8 groups x 32 slices; 384 threads = (gl 0..23 = row) x (ks 0..15).
// Weights: TWO f32 arrays (R and N), row stride 769 (== 1 mod 32): a wave's
// b128 reads at dword addr gl*769 + 4ks + 64j land 2 lanes/bank -> FREE
// (R12's pair-layout was 8-way conflicted: 9.3e8 SQ_LDS_BANK_CONFLICT).
// hs: 4x768 f32 single buffer. Protocol unchanged (R3/R8-proven).
__global__ __launch_bounds__(THRS) void k_scan(const float* __restrict__ Whh,
                                               const float* __restrict__ bhh,
                                               const float* __restrict__ giR,
                                               float* __restrict__ out,   // giN in, h out
                                               unsigned* __restrict__ ring) {
    extern __shared__ char smem[];
    float* wldsR = (float*)smem;                       // [RPW][WSTR]
    float* wldsN = wldsR + RPW * WSTR;                 // [RPW][WSTR]
    float* hs    = wldsN + RPW * WSTR;                 // [BPG*Hd]

    const int tid = threadIdx.x;
    const int gl  = tid >> 4;          // 0..23 = local row
    const int ks  = tid & 15;          // 0..15 = k-slice
    const int grp = blockIdx.x >> 5;   // 0..7
    const int s   = blockIdx.x & 31;   // 0..31
    const int b0  = grp * BPG;
    const int g   = s * RPW + gl;      // global row 0..767
    unsigned* ringp = ring + (size_t)grp * RINGD * RVALS;

    // ---- one-time: stage weights into LDS (separate R / N arrays) ----
    #pragma unroll
    for (int j = 0; j < 12; ++j) {
        const int kb = (ks << 2) + (j << 6);
        float4 a = *(const float4*)(Whh + (size_t)g * Hd + kb);
        float4 b = *(const float4*)(Whh + (size_t)(2 * Hd + g) * Hd + kb);
        *(float4*)&wldsR[gl * WSTR + kb] = a;
        *(float4*)&wldsN[gl * WSTR + kb] = b;
    }

    // per-output-lane state: lanes ks<4 own (row g, batch bb=ks)
    const int obb = ks;                 // valid when ks<4
    float obr = 0.f, obn = 0.f, gRv = 0.f, gNv = 0.f;
    if (ks < 4) {
        obr = bhh[g];
        obn = bhh[2 * Hd + g];
        const size_t mi = ((size_t)(b0 + obb) * Td) * Hd + g;
        gRv = giR[mi];
        gNv = out[mi];
    }
    __syncthreads();   // weights staged

    for (int t = 0; t < Td; ++t) {
        // ---- poll own 8 words (2 dwordx4) of region t%4 ----
        const unsigned* myp = ringp + (t & 3) * RVALS + (tid << 3);
        u32x4 w0, w1;
        asm volatile(
            "global_load_dwordx4 %0, %2, off sc0 sc1\n\t"
            "global_load_dwordx4 %1, %3, off sc0 sc1\n\t"
            "s_waitcnt vmcnt(0)"
            : "=&v"(w0), "=&v"(w1) : "v"(myp), "v"(myp + 4) : "memory");
        while (w0.x == SENT_U || w0.y == SENT_U || w0.z == SENT_U || w0.w == SENT_U ||
               w1.x == SENT_U || w1.y == SENT_U || w1.z == SENT_U || w1.w == SENT_U) {
            __builtin_amdgcn_s_sleep(1);
            asm volatile(
                "global_load_dwordx4 %0, %2, off sc0 sc1\n\t"
                "global_load_dwordx4 %1, %3, off sc0 sc1\n\t"
                "s_waitcnt vmcnt(0)"
                : "=&v"(w0), "=&v"(w1) : "v"(myp), "v"(myp + 4) : "memory");
        }
        *(u32x4*)((unsigned*)hs + (tid << 3))     = w0;
        *(u32x4*)((unsigned*)hs + (tid << 3) + 4) = w1;

        // ---- reset own produce word in region (t+2)%4 + gi prefetch t+1 ----
        float gR2 = 0.f, gN2 = 0.f;
        if (ks < 4) {
            const unsigned* rp = ringp + ((t + 2) & 3) * RVALS + obb * Hd + g;
            unsigned sv = SENT_U;
            asm volatile("global_store_dword %0, %1, off sc0 sc1"
                         :: "v"(rp), "v"(sv) : "memory");
            if (t + 1 < Td) {
                const size_t mi = ((size_t)(b0 + obb) * Td + (t + 1)) * Hd + g;
                gR2 = giR[mi];
                gN2 = out[mi];
            }
        }

        __syncthreads();   // hs staged

        // ---- matvec: row gl, k-slice ks, 4 batches, scalar fma ----
        float aR[4] = {0.f, 0.f, 0.f, 0.f};
        float aN[4] = {0.f, 0.f, 0.f, 0.f};
        #pragma unroll
        for (int j = 0; j < 12; ++j) {
            const int kb = (ks << 2) + (j << 6);
            const float4 wr4 = *(const float4*)&wldsR[gl * WSTR + kb];
            const float4 wn4 = *(const float4*)&wldsN[gl * WSTR + kb];
            #pragma unroll
            for (int b = 0; b < 4; ++b) {
                const float4 h4 = *(const float4*)&hs[b * Hd + kb];
                aR[b] = fmaf(h4.x, wr4.x, aR[b]); aN[b] = fmaf(h4.x, wn4.x, aN[b]);
                aR[b] = fmaf(h4.y, wr4.y, aR[b]); aN[b] = fmaf(h4.y, wn4.y, aN[b]);
                aR[b] = fmaf(h4.z, wr4.z, aR[b]); aN[b] = fmaf(h4.z, wn4.z, aN[b]);
                aR[b] = fmaf(h4.w, wr4.w, aR[b]); aN[b] = fmaf(h4.w, wn4.w, aN[b]);
            }
        }
        // butterfly over the 16 ks lanes
        #pragma unroll
        for (int off = 8; off >= 1; off >>= 1) {
            #pragma unroll
            for (int b = 0; b < 4; ++b) {
                aR[b] += __shfl_xor(aR[b], off);
                aN[b] += __shfl_xor(aN[b], off);
            }
        }

        // ---- epilogue on lanes ks<4 (batch = ks; static select) ----
        float hnew = 0.f;
        if (ks < 4) {
            const float aRv = (ks & 2) ? ((ks & 1) ? aR[3] : aR[2])
                                       : ((ks & 1) ? aR[1] : aR[0]);
            const float aNv = (ks & 2) ? ((ks & 1) ? aN[3] : aN[2])
                                       : ((ks & 1) ? aN[1] : aN[0]);
            const float r = 1.f / (1.f + __expf(-(gRv + aRv + obr)));
            hnew = tanhf(gNv + r * (aNv + obn));
            gRv = gR2; gNv = gN2;
        }

        // ---- order reset ack (and gi prefetch) before produce ----
        asm volatile("s_waitcnt vmcnt(0)" ::: "memory");

        // ---- produce h_{t+1} word + out[:,t] ----
        if (ks < 4) {
            const unsigned* dp = ringp + ((t + 1) & 3) * RVALS + obb * Hd + g;
            const unsigned hbits = __float_as_uint(hnew);
            asm volatile("global_store_dword %0, %1, off sc0 sc1"
                         :: "v"(dp), "v"(hbits) : "memory");
            out[((size_t)(b0 + obb) * Td + t) * Hd + g] = hnew;
        }

        __syncthreads();   // all hs reads done before next-iter overwrite
    }
}

extern "C" void kernel_launch(void* const* d_in, const int* in_sizes, int n_in,
                              void* d_out, int out_size, void* d_ws, size_t ws_size,
                              hipStream_t stream) {
    const float* input  = (const float*)d_in[0];
    const float* hidden = (const float*)d_in[1];
    const float* Wih    = (const float*)d_in[2];
    const float* Whh    = (const float*)d_in[3];
    const float* bih    = (const float*)d_in[4];
    const float* bhh    = (const float*)d_in[5];
    float* out = (float*)d_out;

    float*    giR  = (float*)d_ws;
    unsigned* ring = (unsigned*)(giR + (size_t)Md * Hd);

    hipFuncSetAttribute((const void*)k_scan,
                        hipFuncAttributeMaxDynamicSharedMemorySize, SMEM_BYTES);

    k_init<<<(NGRP * RINGD * RVALS) / 256, 256, 0, stream>>>(hidden, ring);
    k_gemm<<<512 * 12, 256, 0, stream>>>(input, Wih, bih, giR, out);
    k_scan<<<NGRP * SPW, THRS, SMEM_BYTES, stream>>>(Whh, bhh, giR, out, ring);
}

// Round 14
// 6628.900 us; speedup vs baseline: 1.3141x; 1.3141x over previous
//
#include <hip/hip_runtime.h>
#include <hip/hip_bf16.h>

#define Hd 768
#define Bd 32
#define Td 1024
#define Md (Bd*Td)

// scan: 16 independent groups (1 batch-pair each) x 16 WGs (48 g-rows each)
#define NPAIR 16
#define SPW   16
#define GPW   48
#define THRS  384
#define RINGD 4
#define SENT_U 0x7FC00000u
#define RVALS (2*Hd)    // 1536 words per ring region

typedef unsigned int u32x4 __attribute__((ext_vector_type(4)));
typedef float f32x2 __attribute__((ext_vector_type(2)));

static __device__ __forceinline__ f32x2 splat2(float v) { f32x2 r; r.x = v; r.y = v; return r; }

// ---------------- init: ring region 0 = h0, regions 1..3 = sentinel ----------------
__global__ __launch_bounds__(256) void k_init(const float* __restrict__ hid,
                                              unsigned* __restrict__ ring) {
    int i = blockIdx.x * 256 + threadIdx.x;          // 16*4*1536 = 98304 total
    const int p   = i / (RINGD * RVALS);
    const int rem = i % (RINGD * RVALS);
    const int r   = rem / RVALS;
    const int q   = rem % RVALS;
    const int bb  = q / Hd;
    const int k   = q % Hd;
    unsigned v = SENT_U;
    if (r == 0) v = ((const unsigned*)hid)[(p * 2 + bb) * Hd + k];
    ring[i] = v;
}

// ---------------- pack W_hr/W_hn -> u32 {bf16 R (lo), bf16 N (hi)} ----------------
static __device__ __forceinline__ unsigned bf16rne(float f) {
    unsigned x = __float_as_uint(f);
    return (x + 0x7FFFu + ((x >> 16) & 1u)) >> 16;
}
__global__ __launch_bounds__(256) void k_pack(const float* __restrict__ Whh,
                                              unsigned* __restrict__ wpk) {
    int i = blockIdx.x * 256 + threadIdx.x;
    if (i >= Hd * Hd) return;
    const int g = i / Hd, k = i % Hd;
    const unsigned lo = bf16rne(Whh[(size_t)g * Hd + k]);
    const unsigned hi = bf16rne(Whh[(size_t)(2 * Hd + g) * Hd + k]);
    wpk[i] = lo | (hi << 16);
}

// ---------------- phase 1: gi GEMM (unchanged) ----------------
__global__ __launch_bounds__(256, 2) void k_gemm(const float* __restrict__ A,
                                                 const float* __restrict__ Wih,
                                                 const float* __restrict__ bih,
                                                 float* __restrict__ giR,
                                                 float* __restrict__ giN) {
    __shared__ float As[16][68];
    __shared__ float Brs[16][68];
    __shared__ float Bns[16][68];
    const int tid = threadIdx.x;
    const int mb = blockIdx.x & 511;
    const int nb = blockIdx.x >> 9;
    const int lm = tid >> 2;
    const int lk = (tid & 3) << 2;
    const int tx = tid & 15;
    const int ty = tid >> 4;

    const float* pA = A   + (size_t)(mb * 64 + lm) * Hd + lk;
    const float* pR = Wih + (size_t)(nb * 64 + lm) * Hd + lk;
    const float* pN = Wih + (size_t)(2 * Hd + nb * 64 + lm) * Hd + lk;

    float accR[4][4] = {{0.f}};
    float accN[4][4] = {{0.f}};

    for (int kt = 0; kt < Hd; kt += 16) {
        float4 va = *(const float4*)(pA + kt);
        float4 vr = *(const float4*)(pR + kt);
        float4 vn = *(const float4*)(pN + kt);
        __syncthreads();
        As[lk+0][lm]=va.x; As[lk+1][lm]=va.y; As[lk+2][lm]=va.z; As[lk+3][lm]=va.w;
        Brs[lk+0][lm]=vr.x; Brs[lk+1][lm]=vr.y; Brs[lk+2][lm]=vr.z; Brs[lk+3][lm]=vr.w;
        Bns[lk+0][lm]=vn.x; Bns[lk+1][lm]=vn.y; Bns[lk+2][lm]=vn.z; Bns[lk+3][lm]=vn.w;
        __syncthreads();
        #pragma unroll
        for (int k = 0; k < 16; ++k) {
            float4 a4 = *(const float4*)&As[k][ty << 2];
            float4 r4 = *(const float4*)&Brs[k][tx << 2];
            float4 n4 = *(const float4*)&Bns[k][tx << 2];
            float av[4] = {a4.x, a4.y, a4.z, a4.w};
            float rv[4] = {r4.x, r4.y, r4.z, r4.w};
            float nv[4] = {n4.x, n4.y, n4.z, n4.w};
            #pragma unroll
            for (int i = 0; i < 4; ++i)
                #pragma unroll
                for (int j = 0; j < 4; ++j) {
                    accR[i][j] += av[i] * rv[j];
                    accN[i][j] += av[i] * nv[j];
                }
        }
    }

    const int m0 = mb * 64 + (ty << 2);
    const int g0 = nb * 64 + (tx << 2);
    float4 bR = *(const float4*)(bih + g0);
    float4 bN = *(const float4*)(bih + 2 * Hd + g0);
    #pragma unroll
    for (int i = 0; i < 4; ++i) {
        float4 oR = { accR[i][0]+bR.x, accR[i][1]+bR.y, accR[i][2]+bR.z, accR[i][3]+bR.w };
        float4 oN = { accN[i][0]+bN.x, accN[i][1]+bN.y, accN[i][2]+bN.z, accN[i][3]+bN.w };
        *(float4*)(giR + (size_t)(m0 + i) * Hd + g0) = oR;
        *(float4*)(giN + (size_t)(m0 + i) * Hd + g0) = oN;
    }
}

// ---- macro machinery: per-step streamed weights, 24 named u32x4 ----
#define ALLJ(M, q) M(q,0) M(q,1) M(q,2) M(q,3) M(q,4) M(q,5) M(q,6) M(q,7) M(q,8) M(q,9) M(q,10) M(q,11)

#define WDECL(q,j) u32x4 w##q##_##j;
// plain cached load (no sc bits) -> hits per-XCD L2 after first step
#define WISSUE(q,j) asm volatile("global_load_dwordx4 %0, %1, off" \
    : "=v"(w##q##_##j) : "v"(pw##q + (j << 6)) : "memory");

#define CVT1(q,j,C,HC0,HC1) { \
    const unsigned _p = w##q##_##j.C; \
    f32x2 _wv; _wv.x = __uint_as_float(_p << 16); _wv.y = __uint_as_float(_p & 0xFFFF0000u); \
    a##q##_0 = __builtin_elementwise_fma(splat2(HC0), _wv, a##q##_0); \
    a##q##_1 = __builtin_elementwise_fma(splat2(HC1), _wv, a##q##_1); }

#define DOJ(q,j) { \
    const float4 _h0 = *(const float4*)&hsl[kofs + (j << 6)]; \
    const float4 _h1 = *(const float4*)&hsl[Hd + kofs + (j << 6)]; \
    CVT1(q,j,x,_h0.x,_h1.x) CVT1(q,j,y,_h0.y,_h1.y) \
    CVT1(q,j,z,_h0.z,_h1.z) CVT1(q,j,w,_h0.w,_h1.w) }

#define BFLY(A) \
    A.x += __shfl_xor(A.x, 8); A.y += __shfl_xor(A.y, 8); \
    A.x += __shfl_xor(A.x, 4); A.y += __shfl_xor(A.y, 4); \
    A.x += __shfl_xor(A.x, 2); A.y += __shfl_xor(A.y, 2); \
    A.x += __shfl_xor(A.x, 1); A.y += __shfl_xor(A.y, 1);

// ---------------- phase 2: R7 structure + explicit bf16 weight streaming ----
// 256 WGs = 16 pairs x 16 slices; 384 threads = (gl 0..23) x (ks 0..15).
// Per step: poll own 16B slot -> LDS (parity dbuf) -> ONE barrier ->
// [reset own slot (t+2) | issue 24 w-loads | issue 2 gi loads] ->
// vmcnt(14) compute sub0 -> vmcnt(2) compute sub1 -> butterfly ->
// vmcnt(0) (orders reset ack before produce; gi ready) -> epilogue+produce.
// No end barrier: hs parity dbuf + poll gating bounds skew at 2 (R7-proven).
__global__ __launch_bounds__(THRS)
__attribute__((amdgpu_waves_per_eu(2, 2)))
void k_scan(const unsigned* __restrict__ wpk,
            const float* __restrict__ bhh,
            const float* __restrict__ giR,
            float* __restrict__ out,   // giN in, h out
            unsigned* __restrict__ ring) {
    __shared__ float hs[2 * RVALS];
    const int tid = threadIdx.x;
    const int gl  = tid >> 4;          // 0..23
    const int ks  = tid & 15;          // 0..15
    const int p   = blockIdx.x >> 4;   // pair 0..15
    const int s   = blockIdx.x & 15;   // slice 0..15
    const int b0  = p * 2;
    const int kofs = ks << 2;
    unsigned* ringp = ring + (size_t)p * RINGD * RVALS;

    // weight row pointers (u32 pairs): sub0 row = s*48+gl, sub1 row = +24
    const unsigned* pw0 = wpk + (size_t)(s * GPW + gl) * Hd + kofs;
    const unsigned* pw1 = wpk + (size_t)(s * GPW + 24 + gl) * Hd + kofs;

    // per-output-lane state (lanes ks<4 own (sub=ks&1, bb=ks>>1))
    const int osub = ks & 1, obb = ks >> 1;
    const int og   = s * GPW + osub * 24 + gl;
    float obr = 0.f, obn = 0.f, gRv = 0.f, gNv = 0.f;
    if (ks < 4) {
        obr = bhh[og];
        obn = bhh[2 * Hd + og];
        const size_t mi = ((size_t)(b0 + obb) * Td) * Hd + og;
        gRv = giR[mi];
        gNv = out[mi];
    }

    for (int t = 0; t < Td; ++t) {
        // ---- B. poll own dwordx4 slot of region t%4 ----
        const unsigned* myp = ringp + (t & 3) * RVALS + (tid << 2);
        float* hsl = hs + (t & 1) * RVALS;
        u32x4 w;
        asm volatile("global_load_dwordx4 %0, %1, off sc0 sc1\n\ts_waitcnt vmcnt(0)"
                     : "=v"(w) : "v"(myp) : "memory");
        while (w.x == SENT_U || w.y == SENT_U || w.z == SENT_U || w.w == SENT_U) {
            __builtin_amdgcn_s_sleep(1);
            asm volatile("global_load_dwordx4 %0, %1, off sc0 sc1\n\ts_waitcnt vmcnt(0)"
                         : "=v"(w) : "v"(myp) : "memory");
        }
        *(u32x4*)((unsigned*)hsl + (tid << 2)) = w;

        // ---- D. staging complete (barrier drains only lgkm + retired polls) ----
        __syncthreads();

        // ---- E1. reset own slot of region (t+2)%4 [1 outstanding] ----
        {
            const unsigned* rp = ringp + ((t + 2) & 3) * RVALS + (tid << 2);
            u32x4 sv = { SENT_U, SENT_U, SENT_U, SENT_U };
            asm volatile("global_store_dwordx4 %0, %1, off sc0 sc1"
                         :: "v"(rp), "v"(sv) : "memory");
        }

        // ---- E2. issue 24 weight loads [25 outstanding] ----
        WDECL(0,0) WDECL(0,1) WDECL(0,2) WDECL(0,3) WDECL(0,4) WDECL(0,5)
        WDECL(0,6) WDECL(0,7) WDECL(0,8) WDECL(0,9) WDECL(0,10) WDECL(0,11)
        WDECL(1,0) WDECL(1,1) WDECL(1,2) WDECL(1,3) WDECL(1,4) WDECL(1,5)
        WDECL(1,6) WDECL(1,7) WDECL(1,8) WDECL(1,9) WDECL(1,10) WDECL(1,11)
        ALLJ(WISSUE, 0)
        ALLJ(WISSUE, 1)

        // ---- E3. gi prefetch, ALWAYS 2 loads/wave (clamped) [27 outstanding] ----
        float gR2 = 0.f, gN2 = 0.f;
        {
            const int tn = (t + 1 < Td) ? t + 1 : t;
            if (ks < 4) {
                const size_t mi = ((size_t)(b0 + obb) * Td + tn) * Hd + og;
                asm volatile("global_load_dword %0, %1, off"
                             : "=v"(gR2) : "v"(giR + mi) : "memory");
                asm volatile("global_load_dword %0, %1, off"
                             : "=v"(gN2) : "v"(out + mi) : "memory");
            }
        }

        // ---- wait sub0 weights (reset+w0 retired; w1+gi=14 outstanding) ----
        asm volatile("s_waitcnt vmcnt(14)" ::: "memory");
        __builtin_amdgcn_sched_barrier(0);

        f32x2 a0_0 = splat2(0.f), a0_1 = splat2(0.f);
        f32x2 a1_0 = splat2(0.f), a1_1 = splat2(0.f);
        ALLJ(DOJ, 0)

        // ---- wait sub1 weights (gi may remain) ----
        asm volatile("s_waitcnt vmcnt(2)" ::: "memory");
        __builtin_amdgcn_sched_barrier(0);
        ALLJ(DOJ, 1)

        BFLY(a0_0) BFLY(a0_1) BFLY(a1_0) BFLY(a1_1)

        // ---- G. drain all (reset ack ordered before produce; gi ready) ----
        asm volatile("s_waitcnt vmcnt(0)" ::: "memory");
        __builtin_amdgcn_sched_barrier(0);

        // ---- F/H. epilogue + produce h_{t+1} + out[:,t] ----
        if (ks < 4) {
            f32x2 mine = osub ? (obb ? a1_1 : a1_0) : (obb ? a0_1 : a0_0);
            const float r = 1.f / (1.f + __expf(-(gRv + mine.x + obr)));
            const float hnew = tanhf(gNv + r * (mine.y + obn));
            gRv = gR2; gNv = gN2;
            const unsigned* dp = ringp + ((t + 1) & 3) * RVALS + obb * Hd + og;
            const unsigned hbits = __float_as_uint(hnew);
            asm volatile("global_store_dword %0, %1, off sc0 sc1"
                         :: "v"(dp), "v"(hbits) : "memory");
            out[((size_t)(b0 + obb) * Td + t) * Hd + og] = hnew;
        }
        // no end barrier: parity dbuf + poll gating bound skew (R7-proven)
    }
}

extern "C" void kernel_launch(void* const* d_in, const int* in_sizes, int n_in,
                              void* d_out, int out_size, void* d_ws, size_t ws_size,
                              hipStream_t stream) {
    const float* input  = (const float*)d_in[0];
    const float* hidden = (const float*)d_in[1];
    const float* Wih    = (const float*)d_in[2];
    const float* Whh    = (const float*)d_in[3];
    const float* bih    = (const float*)d_in[4];
    const float* bhh    = (const float*)d_in[5];
    float* out = (float*)d_out;

    // ws layout: gi_r (M*H f32) | ring (16*4*1536 u32) | wpk (768*768 u32)
    float*    giR  = (float*)d_ws;
    unsigned* ring = (unsigned*)(giR + (size_t)Md * Hd);
    unsigned* wpk  = ring + (size_t)NPAIR * RINGD * RVALS;

    k_init<<<(NPAIR * RINGD * RVALS) / 256, 256, 0, stream>>>(hidden, ring);
    k_pack<<<(Hd * Hd + 255) / 256, 256, 0, stream>>>(Whh, wpk);
    k_gemm<<<512 * 12, 256, 0, stream>>>(input, Wih, bih, giR, out);
    k_scan<<<NPAIR * SPW, THRS, 0, stream>>>(wpk, bhh, giR, out, ring);
}

// Round 15
// 5512.733 us; speedup vs baseline: 1.5802x; 1.2025x over previous
//
#include <hip/hip_runtime.h>
#include <hip/hip_bf16.h>

#define Hd 768
#define Bd 32
#define Td 1024
#define Md (Bd*Td)

// scan: 16 independent groups (1 batch-pair each) x 16 WGs (48 g-rows each)
#define NPAIR 16
#define SPW   16
#define GPW   48
#define THRS  384
#define RINGD 4
#define SENT_U 0x7FC00000u
#define RVALS (2*Hd)    // 1536 words per ring region

typedef unsigned int u32x4 __attribute__((ext_vector_type(4)));
typedef float f32x2 __attribute__((ext_vector_type(2)));

static __device__ __forceinline__ f32x2 splat2(float v) { f32x2 r; r.x = v; r.y = v; return r; }

// ---------------- init: ring region 0 = h0, regions 1..3 = sentinel ----------------
__global__ __launch_bounds__(256) void k_init(const float* __restrict__ hid,
                                              unsigned* __restrict__ ring) {
    int i = blockIdx.x * 256 + threadIdx.x;          // 16*4*1536 = 98304 total
    const int p   = i / (RINGD * RVALS);
    const int rem = i % (RINGD * RVALS);
    const int r   = rem / RVALS;
    const int q   = rem % RVALS;
    const int bb  = q / Hd;
    const int k   = q % Hd;
    unsigned v = SENT_U;
    if (r == 0) v = ((const unsigned*)hid)[(p * 2 + bb) * Hd + k];
    ring[i] = v;
}

// ---------------- pack W_hr/W_hn -> u32 {bf16 R (lo), bf16 N (hi)} ----------------
static __device__ __forceinline__ unsigned bf16rne(float f) {
    unsigned x = __float_as_uint(f);
    return (x + 0x7FFFu + ((x >> 16) & 1u)) >> 16;
}
__global__ __launch_bounds__(256) void k_pack(const float* __restrict__ Whh,
                                              unsigned* __restrict__ wpk) {
    int i = blockIdx.x * 256 + threadIdx.x;
    if (i >= Hd * Hd) return;
    const int g = i / Hd, k = i % Hd;
    const unsigned lo = bf16rne(Whh[(size_t)g * Hd + k]);
    const unsigned hi = bf16rne(Whh[(size_t)(2 * Hd + g) * Hd + k]);
    wpk[i] = lo | (hi << 16);
}

// ---------------- phase 1: gi GEMM (unchanged) ----------------
__global__ __launch_bounds__(256, 2) void k_gemm(const float* __restrict__ A,
                                                 const float* __restrict__ Wih,
                                                 const float* __restrict__ bih,
                                                 float* __restrict__ giR,
                                                 float* __restrict__ giN) {
    __shared__ float As[16][68];
    __shared__ float Brs[16][68];
    __shared__ float Bns[16][68];
    const int tid = threadIdx.x;
    const int mb = blockIdx.x & 511;
    const int nb = blockIdx.x >> 9;
    const int lm = tid >> 2;
    const int lk = (tid & 3) << 2;
    const int tx = tid & 15;
    const int ty = tid >> 4;

    const float* pA = A   + (size_t)(mb * 64 + lm) * Hd + lk;
    const float* pR = Wih + (size_t)(nb * 64 + lm) * Hd + lk;
    const float* pN = Wih + (size_t)(2 * Hd + nb * 64 + lm) * Hd + lk;

    float accR[4][4] = {{0.f}};
    float accN[4][4] = {{0.f}};

    for (int kt = 0; kt < Hd; kt += 16) {
        float4 va = *(const float4*)(pA + kt);
        float4 vr = *(const float4*)(pR + kt);
        float4 vn = *(const float4*)(pN + kt);
        __syncthreads();
        As[lk+0][lm]=va.x; As[lk+1][lm]=va.y; As[lk+2][lm]=va.z; As[lk+3][lm]=va.w;
        Brs[lk+0][lm]=vr.x; Brs[lk+1][lm]=vr.y; Brs[lk+2][lm]=vr.z; Brs[lk+3][lm]=vr.w;
        Bns[lk+0][lm]=vn.x; Bns[lk+1][lm]=vn.y; Bns[lk+2][lm]=vn.z; Bns[lk+3][lm]=vn.w;
        __syncthreads();
        #pragma unroll
        for (int k = 0; k < 16; ++k) {
            float4 a4 = *(const float4*)&As[k][ty << 2];
            float4 r4 = *(const float4*)&Brs[k][tx << 2];
            float4 n4 = *(const float4*)&Bns[k][tx << 2];
            float av[4] = {a4.x, a4.y, a4.z, a4.w};
            float rv[4] = {r4.x, r4.y, r4.z, r4.w};
            float nv[4] = {n4.x, n4.y, n4.z, n4.w};
            #pragma unroll
            for (int i = 0; i < 4; ++i)
                #pragma unroll
                for (int j = 0; j < 4; ++j) {
                    accR[i][j] += av[i] * rv[j];
                    accN[i][j] += av[i] * nv[j];
                }
        }
    }

    const int m0 = mb * 64 + (ty << 2);
    const int g0 = nb * 64 + (tx << 2);
    float4 bR = *(const float4*)(bih + g0);
    float4 bN = *(const float4*)(bih + 2 * Hd + g0);
    #pragma unroll
    for (int i = 0; i < 4; ++i) {
        float4 oR = { accR[i][0]+bR.x, accR[i][1]+bR.y, accR[i][2]+bR.z, accR[i][3]+bR.w };
        float4 oN = { accN[i][0]+bN.x, accN[i][1]+bN.y, accN[i][2]+bN.z, accN[i][3]+bN.w };
        *(float4*)(giR + (size_t)(m0 + i) * Hd + g0) = oR;
        *(float4*)(giN + (size_t)(m0 + i) * Hd + g0) = oN;
    }
}

// ---- macro machinery: per-step streamed weights, 24 named u32x4 ----
#define ALLJ(M, q) M(q,0) M(q,1) M(q,2) M(q,3) M(q,4) M(q,5) M(q,6) M(q,7) M(q,8) M(q,9) M(q,10) M(q,11)

#define WDECL(q,j) u32x4 w##q##_##j;
// plain cached load (no sc bits) -> per-XCD L2 hit after first step
#define WISSUE(q,j) asm volatile("global_load_dwordx4 %0, %1, off" \
    : "=v"(w##q##_##j) : "v"(pw##q + (j << 6)) : "memory");

#define CVT1(q,j,C,HC0,HC1) { \
    const unsigned _p = w##q##_##j.C; \
    f32x2 _wv; _wv.x = __uint_as_float(_p << 16); _wv.y = __uint_as_float(_p & 0xFFFF0000u); \
    a##q##_0 = __builtin_elementwise_fma(splat2(HC0), _wv, a##q##_0); \
    a##q##_1 = __builtin_elementwise_fma(splat2(HC1), _wv, a##q##_1); }

#define DOJ(q,j) { \
    const float4 _h0 = *(const float4*)&hsl[kofs + (j << 6)]; \
    const float4 _h1 = *(const float4*)&hsl[Hd + kofs + (j << 6)]; \
    CVT1(q,j,x,_h0.x,_h1.x) CVT1(q,j,y,_h0.y,_h1.y) \
    CVT1(q,j,z,_h0.z,_h1.z) CVT1(q,j,w,_h0.w,_h1.w) }

#define BFLY(A) \
    A.x += __shfl_xor(A.x, 8); A.y += __shfl_xor(A.y, 8); \
    A.x += __shfl_xor(A.x, 4); A.y += __shfl_xor(A.y, 4); \
    A.x += __shfl_xor(A.x, 2); A.y += __shfl_xor(A.y, 2); \
    A.x += __shfl_xor(A.x, 1); A.y += __shfl_xor(A.y, 1);

// ---------------- phase 2: R7 overlap structure + explicit bf16 streaming ----
// 256 WGs = 16 pairs x 16 slices; 384 threads = (gl 0..23) x (ks 0..15).
// Per step:
//   A.  issue 24 weight loads + 2 gi loads (plain) BEFORE the poll
//       -> L2 latency/stream hides under the producer wait (R14 regression fix)
//   B.  poll own 16B slot (sc0sc1; vmcnt(0)/round drains weights+gi for free)
//       stage to LDS parity buffer
//   D.  __syncthreads (no outstanding vmem -> no hidden drain)
//   C.  lanes ks<4: reset own produce word in region (t+2)%4 (ack rides compute)
//   E.  compute from in-register weights + LDS h; butterfly
//   G.  vmcnt(0)   (orders C's reset ack before H; long retired by now)
//   H.  lanes ks<4: epilogue + produce (sc0sc1) + out (plain)
// Skew bound: mid-step barrier + parity hs dbuf + full-region poll (R7-proven).
// Reset@t+2 -> vmcnt -> produce@t+1 invariant: R3/R8-proven.
__global__ __launch_bounds__(THRS)
__attribute__((amdgpu_waves_per_eu(2, 2)))
void k_scan(const unsigned* __restrict__ wpk,
            const float* __restrict__ bhh,
            const float* __restrict__ giR,
            float* __restrict__ out,   // giN in, h out
            unsigned* __restrict__ ring) {
    __shared__ float hs[2 * RVALS];
    const int tid = threadIdx.x;
    const int gl  = tid >> 4;          // 0..23
    const int ks  = tid & 15;          // 0..15
    const int p   = blockIdx.x >> 4;   // pair 0..15
    const int s   = blockIdx.x & 15;   // slice 0..15
    const int b0  = p * 2;
    const int kofs = ks << 2;
    unsigned* ringp = ring + (size_t)p * RINGD * RVALS;

    // weight row pointers (u32 pairs): sub0 row = s*48+gl, sub1 row = +24
    const unsigned* pw0 = wpk + (size_t)(s * GPW + gl) * Hd + kofs;
    const unsigned* pw1 = wpk + (size_t)(s * GPW + 24 + gl) * Hd + kofs;

    // per-output-lane state (lanes ks<4 own (sub=ks&1, bb=ks>>1))
    const int osub = ks & 1, obb = ks >> 1;
    const int og   = s * GPW + osub * 24 + gl;
    float obr = 0.f, obn = 0.f, gRv = 0.f, gNv = 0.f;
    if (ks < 4) {
        obr = bhh[og];
        obn = bhh[2 * Hd + og];
        const size_t mi = ((size_t)(b0 + obb) * Td) * Hd + og;
        gRv = giR[mi];
        gNv = out[mi];
    }

    for (int t = 0; t < Td; ++t) {
        // ---- A. issue weight loads (this step) + gi loads (next step) ----
        WDECL(0,0) WDECL(0,1) WDECL(0,2) WDECL(0,3) WDECL(0,4) WDECL(0,5)
        WDECL(0,6) WDECL(0,7) WDECL(0,8) WDECL(0,9) WDECL(0,10) WDECL(0,11)
        WDECL(1,0) WDECL(1,1) WDECL(1,2) WDECL(1,3) WDECL(1,4) WDECL(1,5)
        WDECL(1,6) WDECL(1,7) WDECL(1,8) WDECL(1,9) WDECL(1,10) WDECL(1,11)
        ALLJ(WISSUE, 0)
        ALLJ(WISSUE, 1)
        float gR2 = 0.f, gN2 = 0.f;
        if (ks < 4) {
            const int tn = (t + 1 < Td) ? t + 1 : t;
            const size_t mi = ((size_t)(b0 + obb) * Td + tn) * Hd + og;
            asm volatile("global_load_dword %0, %1, off"
                         : "=v"(gR2) : "v"(giR + mi) : "memory");
            asm volatile("global_load_dword %0, %1, off"
                         : "=v"(gN2) : "v"(out + mi) : "memory");
        }

        // ---- B. poll own dwordx4 slot of region t%4 (drains A for free) ----
        const unsigned* myp = ringp + (t & 3) * RVALS + (tid << 2);
        float* hsl = hs + (t & 1) * RVALS;
        u32x4 w;
        asm volatile("global_load_dwordx4 %0, %1, off sc0 sc1\n\ts_waitcnt vmcnt(0)"
                     : "=v"(w) : "v"(myp) : "memory");
        while (w.x == SENT_U || w.y == SENT_U || w.z == SENT_U || w.w == SENT_U) {
            __builtin_amdgcn_s_sleep(1);
            asm volatile("global_load_dwordx4 %0, %1, off sc0 sc1\n\ts_waitcnt vmcnt(0)"
                         : "=v"(w) : "v"(myp) : "memory");
        }
        *(u32x4*)((unsigned*)hsl + (tid << 2)) = w;

        // ---- D. staging complete (zero outstanding vmem here) ----
        __syncthreads();

        // ---- C. reset own produce word in region (t+2)%4 ----
        if (ks < 4) {
            const unsigned* rp = ringp + ((t + 2) & 3) * RVALS + obb * Hd + og;
            unsigned sv = SENT_U;
            asm volatile("global_store_dword %0, %1, off sc0 sc1"
                         :: "v"(rp), "v"(sv) : "memory");
        }

        // ---- E. matvec from in-register bf16 weights + LDS h ----
        f32x2 a0_0 = splat2(0.f), a0_1 = splat2(0.f);
        f32x2 a1_0 = splat2(0.f), a1_1 = splat2(0.f);
        ALLJ(DOJ, 0)
        ALLJ(DOJ, 1)
        BFLY(a0_0) BFLY(a0_1) BFLY(a1_0) BFLY(a1_1)

        // ---- G. order reset ack before produce (retired under E) ----
        asm volatile("s_waitcnt vmcnt(0)" ::: "memory");
        __builtin_amdgcn_sched_barrier(0);

        // ---- H. epilogue + produce h_{t+1} + out[:,t] ----
        if (ks < 4) {
            f32x2 mine = osub ? (obb ? a1_1 : a1_0) : (obb ? a0_1 : a0_0);
            const float r = 1.f / (1.f + __expf(-(gRv + mine.x + obr)));
            const float hnew = tanhf(gNv + r * (mine.y + obn));
            gRv = gR2; gNv = gN2;
            const unsigned* dp = ringp + ((t + 1) & 3) * RVALS + obb * Hd + og;
            const unsigned hbits = __float_as_uint(hnew);
            asm volatile("global_store_dword %0, %1, off sc0 sc1"
                         :: "v"(dp), "v"(hbits) : "memory");
            out[((size_t)(b0 + obb) * Td + t) * Hd + og] = hnew;
        }
        // no end barrier: parity dbuf + mid-step barrier bound skew (R7-proven)
    }
}

extern "C" void kernel_launch(void* const* d_in, const int* in_sizes, int n_in,
                              void* d_out, int out_size, void* d_ws, size_t ws_size,
                              hipStream_t stream) {
    const float* input  = (const float*)d_in[0];
    const float* hidden = (const float*)d_in[1];
    const float* Wih    = (const float*)d_in[2];
    const float* Whh    = (const float*)d_in[3];
    const float* bih    = (const float*)d_in[4];
    const float* bhh    = (const float*)d_in[5];
    float* out = (float*)d_out;

    // ws layout: gi_r (M*H f32) | ring (16*4*1536 u32) | wpk (768*768 u32)
    float*    giR  = (float*)d_ws;
    unsigned* ring = (unsigned*)(giR + (size_t)Md * Hd);
    unsigned* wpk  = ring + (size_t)NPAIR * RINGD * RVALS;

    k_init<<<(NPAIR * RINGD * RVALS) / 256, 256, 0, stream>>>(hidden, ring);
    k_pack<<<(Hd * Hd + 255) / 256, 256, 0, stream>>>(Whh, wpk);
    k_gemm<<<512 * 12, 256, 0, stream>>>(input, Wih, bih, giR, out);
    k_scan<<<NPAIR * SPW, THRS, 0, stream>>>(wpk, bhh, giR, out, ring);
}